// Round 1
// baseline (1315.756 us; speedup 1.0000x reference)
//
#include <hip/hip_runtime.h>

// OnsetLSTM: 2-layer LSTM, B=256, T=512, D=160, H=128.
// Design: one block per batch row (256 blocks), 512 threads = one gate column
// each. Weights live in VGPRs as packed f16 pairs; h broadcast via LDS.
// Recurrence is block-local -> zero inter-block sync, 2 kernel launches total.

typedef _Float16 half2_t __attribute__((ext_vector_type(2)));

#define T_STEPS 512
#define HID     128
#define NGATES  512

static __device__ __forceinline__ unsigned pack2(float a, float b) {
  half2_t h;
  h[0] = (_Float16)a;
  h[1] = (_Float16)b;
  return __builtin_bit_cast(unsigned, h);
}

static __device__ __forceinline__ float dot2f(unsigned a, unsigned b, float c) {
#if __has_builtin(__builtin_amdgcn_fdot2)
  return __builtin_amdgcn_fdot2(__builtin_bit_cast(half2_t, a),
                                __builtin_bit_cast(half2_t, b), c, false);
#else
  half2_t x = __builtin_bit_cast(half2_t, a);
  half2_t y = __builtin_bit_cast(half2_t, b);
  // fpext+fma pattern -> v_fma_mix_f32 fusion, fp32 accumulate
  float r = c;
  r = fmaf((float)x[0], (float)y[0], r);
  r = fmaf((float)x[1], (float)y[1], r);
  return r;
#endif
}

static __device__ __forceinline__ float sigm(float x) {
  return 1.0f / (1.0f + __expf(-x));
}

static __device__ __forceinline__ float tanh_fast(float x) {
  x = fminf(15.0f, fmaxf(-15.0f, x));
  float e = __expf(2.0f * x);
  return (e - 1.0f) / (e + 1.0f);
}

// KX = input feature count for this layer (160 for L0, 128 for L1).
template <int KX>
__global__ __launch_bounds__(512, 2) void lstm_layer(
    const float* __restrict__ xf,     // L0: fp32 input x [B,T,KX]  (else null)
    const unsigned* __restrict__ xh,  // L1: f16-pair input h1      (else null)
    const float* __restrict__ Wih,    // [512, KX]
    const float* __restrict__ Whh,    // [512, 128]
    const float* __restrict__ bih,    // [512]
    const float* __restrict__ bhh,    // [512]
    const float* __restrict__ h0,     // [B,128] (this layer's slice)
    const float* __restrict__ c0,     // [B,128]
    _Float16* __restrict__ hout,      // L0: h1 buffer [B,T,128] f16 (else null)
    float* __restrict__ out)          // L1: d_out [B,128] fp32      (else null)
{
  constexpr int KXP = KX / 2;   // 80 or 64 packed pairs
  constexpr int KHP = HID / 2;  // 64 packed pairs

  const int b = blockIdx.x;   // batch row
  const int n = threadIdx.x;  // gate column 0..511 (i|f|g|o blocks of 128)

  __shared__ unsigned xbuf[KXP];  // x_t as f16 pairs
  __shared__ unsigned hbuf[KHP];  // h_{t-1} as f16 pairs
  __shared__ float glds[NGATES];  // raw gates

  // --- load this thread's weight rows into registers as packed f16 pairs ---
  unsigned wih[KXP];
  unsigned whh[KHP];
#pragma unroll
  for (int j = 0; j < KXP; ++j)
    wih[j] = pack2(Wih[n * KX + 2 * j], Wih[n * KX + 2 * j + 1]);
#pragma unroll
  for (int j = 0; j < KHP; ++j)
    whh[j] = pack2(Whh[n * HID + 2 * j], Whh[n * HID + 2 * j + 1]);

  const float bias = bih[n] + bhh[n];

  // --- init state ---
  float c = 0.0f;
  if (n < HID) c = c0[b * HID + n];
  if (n < KHP) hbuf[n] = pack2(h0[b * HID + 2 * n], h0[b * HID + 2 * n + 1]);

#pragma unroll 1
  for (int t = 0; t < T_STEPS; ++t) {
    // --- stage x_t into LDS as f16 pairs ---
    if (KX == 160) {
      if (n < KXP) {
        const float* xp = xf + ((long long)b * T_STEPS + t) * KX;
        xbuf[n] = pack2(xp[2 * n], xp[2 * n + 1]);
      }
    } else {
      if (n < KXP) xbuf[n] = xh[((long long)b * T_STEPS + t) * KXP + n];
    }
    __syncthreads();  // xbuf + hbuf ready; also fences prior-step glds reads

    // --- gate n = bias + x.Wih[n] + h.Whh[n]  (fp32 accumulate) ---
    float a0 = bias, a1 = 0.f, a2 = 0.f, a3 = 0.f;
#pragma unroll
    for (int j = 0; j < KXP; j += 4) {
      a0 = dot2f(xbuf[j + 0], wih[j + 0], a0);
      a1 = dot2f(xbuf[j + 1], wih[j + 1], a1);
      a2 = dot2f(xbuf[j + 2], wih[j + 2], a2);
      a3 = dot2f(xbuf[j + 3], wih[j + 3], a3);
    }
#pragma unroll
    for (int j = 0; j < KHP; j += 4) {
      a0 = dot2f(hbuf[j + 0], whh[j + 0], a0);
      a1 = dot2f(hbuf[j + 1], whh[j + 1], a1);
      a2 = dot2f(hbuf[j + 2], whh[j + 2], a2);
      a3 = dot2f(hbuf[j + 3], whh[j + 3], a3);
    }
    glds[n] = (a0 + a1) + (a2 + a3);
    __syncthreads();  // gates ready

    // --- elementwise LSTM cell update (threads 0..127) ---
    if (n < HID) {
      float gi = glds[n];
      float gf = glds[HID + n];
      float gg = glds[2 * HID + n];
      float go = glds[3 * HID + n];
      float iv = sigm(gi);
      float fv = sigm(gf);
      float gv = tanh_fast(gg);
      float ov = sigm(go);
      c = fv * c + iv * gv;
      float h = ov * tanh_fast(c);
      reinterpret_cast<_Float16*>(hbuf)[n] = (_Float16)h;  // next-step h
      if (hout) hout[((long long)b * T_STEPS + t) * HID + n] = (_Float16)h;
      if (out && t == T_STEPS - 1) out[b * HID + n] = h;
    }
    // next iteration's first __syncthreads() fences hbuf write -> read
  }
}

extern "C" void kernel_launch(void* const* d_in, const int* in_sizes, int n_in,
                              void* d_out, int out_size, void* d_ws,
                              size_t ws_size, hipStream_t stream) {
  const float* x    = (const float*)d_in[0];
  const float* h0   = (const float*)d_in[1];   // [2,256,128]
  const float* c0   = (const float*)d_in[2];   // [2,256,128]
  const float* Wih0 = (const float*)d_in[3];   // [512,160]
  const float* Whh0 = (const float*)d_in[4];   // [512,128]
  const float* bih0 = (const float*)d_in[5];
  const float* bhh0 = (const float*)d_in[6];
  const float* Wih1 = (const float*)d_in[7];   // [512,128]
  const float* Whh1 = (const float*)d_in[8];   // [512,128]
  const float* bih1 = (const float*)d_in[9];
  const float* bhh1 = (const float*)d_in[10];

  _Float16* h1 = (_Float16*)d_ws;  // [256,512,128] f16 = 33.5 MB

  lstm_layer<160><<<256, 512, 0, stream>>>(
      x, nullptr, Wih0, Whh0, bih0, bhh0,
      h0, c0, h1, nullptr);

  lstm_layer<128><<<256, 512, 0, stream>>>(
      nullptr, (const unsigned*)d_ws, Wih1, Whh1, bih1, bhh1,
      h0 + 256 * 128, c0 + 256 * 128, nullptr, (float*)d_out);
}

// Round 2
// 1080.596 us; speedup vs baseline: 1.2176x; 1.2176x over previous
//
#include <hip/hip_runtime.h>

// OnsetLSTM: 2-layer LSTM, B=256, T=512, D=160, H=128, fp32 in/out.
// One block per batch row (256 blocks, 512 threads). Both layers fused in a
// single kernel: layer-0's h sequence (512x128 f16 = 128KB) lives in LDS, so
// layer-1 consumes it with zero global traffic. Weights are register-resident
// f16 pairs (one gate row per thread); activations broadcast via LDS; x_t is
// register-prefetched one step ahead (T14) to hide HBM/L2 latency.

typedef _Float16 half2_t __attribute__((ext_vector_type(2)));

#define T_STEPS 512
#define HID     128
#define NGATES  512

static __device__ __forceinline__ unsigned pack2(float a, float b) {
  half2_t h;
  h[0] = (_Float16)a;
  h[1] = (_Float16)b;
  return __builtin_bit_cast(unsigned, h);
}

static __device__ __forceinline__ float dot2f(unsigned a, unsigned b, float c) {
#if __has_builtin(__builtin_amdgcn_fdot2)
  return __builtin_amdgcn_fdot2(__builtin_bit_cast(half2_t, a),
                                __builtin_bit_cast(half2_t, b), c, false);
#else
  half2_t x = __builtin_bit_cast(half2_t, a);
  half2_t y = __builtin_bit_cast(half2_t, b);
  float r = c;
  r = fmaf((float)x[0], (float)y[0], r);
  r = fmaf((float)x[1], (float)y[1], r);
  return r;
#endif
}

static __device__ __forceinline__ float fast_rcp(float x) {
#if __has_builtin(__builtin_amdgcn_rcpf)
  return __builtin_amdgcn_rcpf(x);
#else
  return 1.0f / x;
#endif
}

static __device__ __forceinline__ float fast_exp2(float x) {
#if __has_builtin(__builtin_amdgcn_exp2f)
  return __builtin_amdgcn_exp2f(x);
#else
  return exp2f(x);
#endif
}

// sigm(x) = 1/(1+2^(-x*log2e)) : 1 exp + 1 rcp
static __device__ __forceinline__ float sigm(float x) {
  return fast_rcp(1.0f + fast_exp2(x * -1.44269504f));
}
// tanh(x) = 1 - 2/(2^(2x*log2e)+1) : 1 exp + 1 rcp. Saturates correctly at +-inf.
static __device__ __forceinline__ float tanh_f(float x) {
  float e = fast_exp2(x * 2.885390082f);
  return 1.0f - 2.0f * fast_rcp(e + 1.0f);
}

__global__ __launch_bounds__(512, 1) void lstm_fused(
    const float* __restrict__ x,     // [256,512,160]
    const float* __restrict__ h0,    // [2,256,128]
    const float* __restrict__ c0,    // [2,256,128]
    const float* __restrict__ Wih0,  // [512,160]
    const float* __restrict__ Whh0,  // [512,128]
    const float* __restrict__ bih0, const float* __restrict__ bhh0,
    const float* __restrict__ Wih1,  // [512,128]
    const float* __restrict__ Whh1,  // [512,128]
    const float* __restrict__ bih1, const float* __restrict__ bhh1,
    float* __restrict__ out)         // [256,128]
{
  const int b = blockIdx.x;   // batch row
  const int n = threadIdx.x;  // gate column 0..511 (i|f|g|o blocks of 128)

  __shared__ unsigned h1s[T_STEPS * 64];  // 128KB: layer-0 h sequence, f16 pairs
  __shared__ unsigned xbuf[80];           // layer-0 x_t as f16 pairs
  __shared__ unsigned hbuf[64];           // current layer h_{t-1} as f16 pairs
  __shared__ float glds[NGATES];          // raw gates

  // ===================== Phase 0: layer 0 (KX=160) =====================
  {
    unsigned wih[80];
    unsigned whh[64];
#pragma unroll
    for (int j = 0; j < 80; ++j)
      wih[j] = pack2(Wih0[n * 160 + 2 * j], Wih0[n * 160 + 2 * j + 1]);
#pragma unroll
    for (int j = 0; j < 64; ++j)
      whh[j] = pack2(Whh0[n * HID + 2 * j], Whh0[n * HID + 2 * j + 1]);
    const float bias = bih0[n] + bhh0[n];

    float c = 0.0f;
    if (n < HID) c = c0[b * HID + n];
    if (n < 64) hbuf[n] = pack2(h0[b * HID + 2 * n], h0[b * HID + 2 * n + 1]);

    // prefetch x_0
    float2 xr = make_float2(0.f, 0.f);
    if (n < 80) xr = *(const float2*)&x[((long long)b * T_STEPS + 0) * 160 + 2 * n];

#pragma unroll 1
    for (int t = 0; t < T_STEPS; ++t) {
      if (n < 80) xbuf[n] = pack2(xr.x, xr.y);
      __syncthreads();  // xbuf + hbuf ready

      // issue next step's x load now; consumed next iteration (latency hidden)
      if (n < 80) {
        int tn = (t + 1 < T_STEPS) ? t + 1 : t;
        xr = *(const float2*)&x[((long long)b * T_STEPS + tn) * 160 + 2 * n];
      }

      float a0 = bias, a1 = 0.f, a2 = 0.f, a3 = 0.f;
      const uint4* xb4 = (const uint4*)xbuf;
#pragma unroll
      for (int j = 0; j < 20; ++j) {
        uint4 v = xb4[j];
        a0 = dot2f(v.x, wih[4 * j + 0], a0);
        a1 = dot2f(v.y, wih[4 * j + 1], a1);
        a2 = dot2f(v.z, wih[4 * j + 2], a2);
        a3 = dot2f(v.w, wih[4 * j + 3], a3);
      }
      const uint4* hb4 = (const uint4*)hbuf;
#pragma unroll
      for (int j = 0; j < 16; ++j) {
        uint4 v = hb4[j];
        a0 = dot2f(v.x, whh[4 * j + 0], a0);
        a1 = dot2f(v.y, whh[4 * j + 1], a1);
        a2 = dot2f(v.z, whh[4 * j + 2], a2);
        a3 = dot2f(v.w, whh[4 * j + 3], a3);
      }
      glds[n] = (a0 + a1) + (a2 + a3);
      __syncthreads();  // gates ready

      if (n < HID) {
        float iv = sigm(glds[n]);
        float fv = sigm(glds[HID + n]);
        float gv = tanh_f(glds[2 * HID + n]);
        float ov = sigm(glds[3 * HID + n]);
        c = fv * c + iv * gv;
        float h = ov * tanh_f(c);
        _Float16 hf = (_Float16)h;
        reinterpret_cast<_Float16*>(hbuf)[n] = hf;           // next-step h
        reinterpret_cast<_Float16*>(h1s)[t * HID + n] = hf;  // layer-1 input
      }
      // next iteration's first __syncthreads() fences hbuf/h1s write -> read
    }
  }

  // ===================== Phase 1: layer 1 (KX=128) =====================
  {
    __syncthreads();  // phase-0 writes drained before reseeding hbuf

    unsigned wih[64];
    unsigned whh[64];
#pragma unroll
    for (int j = 0; j < 64; ++j)
      wih[j] = pack2(Wih1[n * HID + 2 * j], Wih1[n * HID + 2 * j + 1]);
#pragma unroll
    for (int j = 0; j < 64; ++j)
      whh[j] = pack2(Whh1[n * HID + 2 * j], Whh1[n * HID + 2 * j + 1]);
    const float bias = bih1[n] + bhh1[n];

    const float* h0b = h0 + 256 * HID;  // layer-1 slices
    const float* c0b = c0 + 256 * HID;
    float c = 0.0f;
    if (n < HID) c = c0b[b * HID + n];
    if (n < 64) hbuf[n] = pack2(h0b[b * HID + 2 * n], h0b[b * HID + 2 * n + 1]);

#pragma unroll 1
    for (int t = 0; t < T_STEPS; ++t) {
      __syncthreads();  // hbuf (and h1s on t=0) ready

      float a0 = bias, a1 = 0.f, a2 = 0.f, a3 = 0.f;
      const uint4* xb4 = (const uint4*)(h1s + t * 64);  // layer-0 h_t from LDS
#pragma unroll
      for (int j = 0; j < 16; ++j) {
        uint4 v = xb4[j];
        a0 = dot2f(v.x, wih[4 * j + 0], a0);
        a1 = dot2f(v.y, wih[4 * j + 1], a1);
        a2 = dot2f(v.z, wih[4 * j + 2], a2);
        a3 = dot2f(v.w, wih[4 * j + 3], a3);
      }
      const uint4* hb4 = (const uint4*)hbuf;
#pragma unroll
      for (int j = 0; j < 16; ++j) {
        uint4 v = hb4[j];
        a0 = dot2f(v.x, whh[4 * j + 0], a0);
        a1 = dot2f(v.y, whh[4 * j + 1], a1);
        a2 = dot2f(v.z, whh[4 * j + 2], a2);
        a3 = dot2f(v.w, whh[4 * j + 3], a3);
      }
      glds[n] = (a0 + a1) + (a2 + a3);
      __syncthreads();  // gates ready

      if (n < HID) {
        float iv = sigm(glds[n]);
        float fv = sigm(glds[HID + n]);
        float gv = tanh_f(glds[2 * HID + n]);
        float ov = sigm(glds[3 * HID + n]);
        c = fv * c + iv * gv;
        float h = ov * tanh_f(c);
        reinterpret_cast<_Float16*>(hbuf)[n] = (_Float16)h;
        if (t == T_STEPS - 1) out[b * HID + n] = h;
      }
    }
  }
}

extern "C" void kernel_launch(void* const* d_in, const int* in_sizes, int n_in,
                              void* d_out, int out_size, void* d_ws,
                              size_t ws_size, hipStream_t stream) {
  const float* x    = (const float*)d_in[0];
  const float* h0   = (const float*)d_in[1];
  const float* c0   = (const float*)d_in[2];
  const float* Wih0 = (const float*)d_in[3];
  const float* Whh0 = (const float*)d_in[4];
  const float* bih0 = (const float*)d_in[5];
  const float* bhh0 = (const float*)d_in[6];
  const float* Wih1 = (const float*)d_in[7];
  const float* Whh1 = (const float*)d_in[8];
  const float* bih1 = (const float*)d_in[9];
  const float* bhh1 = (const float*)d_in[10];

  lstm_fused<<<256, 512, 0, stream>>>(x, h0, c0, Wih0, Whh0, bih0, bhh0,
                                      Wih1, Whh1, bih1, bhh1, (float*)d_out);
}